// Round 8
// baseline (940.785 us; speedup 1.0000x reference)
//
#include <hip/hip_runtime.h>

#define HC 256      // HEADS*HID
#define HEADS 8
#define HID 32
#define GRAPHS 512
#define NEG_SLOPE 0.2f

// ------------------------------------------------------------------
// bf16 helpers (round-to-nearest-even)
__device__ __forceinline__ unsigned short f2bf(float x) {
    unsigned u = __float_as_uint(x);
    return (unsigned short)((u + 0x7fffu + ((u >> 16) & 1u)) >> 16);
}
__device__ __forceinline__ float bf2f(unsigned short b) {
    return __uint_as_float(((unsigned)b) << 16);
}

// async gather: per-lane global src -> LDS at (base + lane*16B)
__device__ __forceinline__ void gld_lds16(const unsigned short* g, unsigned short* l) {
    __builtin_amdgcn_global_load_lds(
        (const __attribute__((address_space(1))) void*)g,
        (__attribute__((address_space(3))) void*)l, 16, 0, 0);
}

// int32/int64 index handling (JAX may emit either for edge_index/batch)
__device__ __forceinline__ int IDX(const void* p, long long i, int mode) {
    if (mode) return (int)((const long long*)p)[i];
    return ((const int*)p)[i];
}

__global__ void detect_kernel(const unsigned int* __restrict__ words, int* __restrict__ mode, int e) {
    __shared__ unsigned int red[256];
    unsigned int v = 0;
    int lim = e < 4096 ? e : 4096;
    for (int i = threadIdx.x; i < lim; i += 256) v |= words[2 * i + 1];
    red[threadIdx.x] = v;
    __syncthreads();
    for (int off = 128; off > 0; off >>= 1) {
        if (threadIdx.x < off) red[threadIdx.x] |= red[threadIdx.x + off];
        __syncthreads();
    }
    if (threadIdx.x == 0) *mode = (red[0] == 0u) ? 1 : 0;  // 1 => int64
}

// ------------------------------------------------------------------
// CSR build: histogram -> scan -> scatter
__global__ void hist_kernel(const void* __restrict__ edge, const int* __restrict__ mode,
                            int* __restrict__ hist, int e) {
    int m = mode[0];
    int i = blockIdx.x * blockDim.x + threadIdx.x;
    if (i < e) atomicAdd(&hist[IDX(edge, (long long)e + i, m)], 1);
}

__global__ void scan1(const int* __restrict__ hist, int* __restrict__ excl,
                      int* __restrict__ bsum, int n) {
    __shared__ int buf[256];
    int i = blockIdx.x * 256 + threadIdx.x;
    int v = (i < n) ? hist[i] : 0;
    buf[threadIdx.x] = v;
    __syncthreads();
    for (int off = 1; off < 256; off <<= 1) {
        int t = (threadIdx.x >= (unsigned)off) ? buf[threadIdx.x - off] : 0;
        __syncthreads();
        buf[threadIdx.x] += t;
        __syncthreads();
    }
    if (i < n) excl[i] = buf[threadIdx.x] - v;
    if (threadIdx.x == 255) bsum[blockIdx.x] = buf[255];
}

__global__ void scan2(int* __restrict__ bsum, int nb) {
    __shared__ int buf[256];
    int v = (threadIdx.x < (unsigned)nb) ? bsum[threadIdx.x] : 0;
    buf[threadIdx.x] = v;
    __syncthreads();
    for (int off = 1; off < 256; off <<= 1) {
        int t = (threadIdx.x >= (unsigned)off) ? buf[threadIdx.x - off] : 0;
        __syncthreads();
        buf[threadIdx.x] += t;
        __syncthreads();
    }
    if (threadIdx.x < (unsigned)nb) bsum[threadIdx.x] = buf[threadIdx.x] - v;  // exclusive
}

__global__ void scan3(int* __restrict__ row_ptr, const int* __restrict__ bsum, int n, int e) {
    int i = blockIdx.x * 256 + threadIdx.x;
    if (i < n) row_ptr[i] += bsum[i >> 8];
    if (i == 0) row_ptr[n] = e;
}

__global__ void scatter_kernel(const void* __restrict__ edge, const int* __restrict__ mode,
                               const int* __restrict__ row_ptr, int* __restrict__ fill,
                               int* __restrict__ outs, int e) {
    int m = mode[0];
    int i = blockIdx.x * blockDim.x + threadIdx.x;
    if (i < e) {
        int d = IDX(edge, (long long)e + i, m);
        int pos = row_ptr[d] + atomicAdd(&fill[d], 1);
        outs[pos] = IDX(edge, (long long)i, m);
    }
}

// ------------------------------------------------------------------
// fp32 GEMM: C[M,256] = A[M,K] @ B[K,256], tile 128x128, 8x8 micro (4+4 split)
// Also emits a node-major bf16 copy of C for the gather table.
__device__ __forceinline__ int bswz(int b) { return b ^ ((b >> 3) & 3); }  // involution

__global__ __launch_bounds__(256) void gemm128(const float* __restrict__ A,
                                               const float* __restrict__ B,
                                               float* __restrict__ C,
                                               unsigned short* __restrict__ C16,
                                               int M, int K) {
    __shared__ float As[16][132];
    __shared__ float Bs[16 * 128];
    const int tid = threadIdx.x;
    const int tx = tid & 15, ty = tid >> 4;
    const int row0 = blockIdx.x * 128, col0 = blockIdx.y * 128;
    const int arow = tid >> 2;
    const int acq = tid & 3;
    const int bc = tid & 31;
    const int bk = tid >> 5;
    float acc[8][8] = {};

    for (int k0 = 0; k0 < K; k0 += 16) {
#pragma unroll
        for (int h = 0; h < 2; ++h) {
            int r = arow + 64 * h;
            float4 a = (row0 + r < M)
                ? *(const float4*)&A[(size_t)(row0 + r) * K + k0 + acq * 4]
                : make_float4(0.f, 0.f, 0.f, 0.f);
            As[acq * 4 + 0][r] = a.x;
            As[acq * 4 + 1][r] = a.y;
            As[acq * 4 + 2][r] = a.z;
            As[acq * 4 + 3][r] = a.w;
        }
#pragma unroll
        for (int h = 0; h < 2; ++h) {
            int kk = bk + 8 * h;
            float4 b = *(const float4*)&B[(size_t)(k0 + kk) * HC + col0 + bc * 4];
            *(float4*)&Bs[kk * 128 + 4 * bswz(bc)] = b;
        }
        __syncthreads();
#pragma unroll
        for (int kk = 0; kk < 16; ++kk) {
            float4 a0 = *(const float4*)&As[kk][ty * 4];
            float4 a1 = *(const float4*)&As[kk][64 + ty * 4];
            float4 b0 = *(const float4*)&Bs[kk * 128 + 4 * bswz(tx)];
            float4 b1 = *(const float4*)&Bs[kk * 128 + 4 * bswz(tx + 16)];
            float av[8] = {a0.x, a0.y, a0.z, a0.w, a1.x, a1.y, a1.z, a1.w};
            float bv[8] = {b0.x, b0.y, b0.z, b0.w, b1.x, b1.y, b1.z, b1.w};
#pragma unroll
            for (int i = 0; i < 8; ++i)
#pragma unroll
                for (int j = 0; j < 8; ++j) acc[i][j] = fmaf(av[i], bv[j], acc[i][j]);
        }
        __syncthreads();
    }
#pragma unroll
    for (int i = 0; i < 8; ++i) {
        int r = row0 + (i < 4 ? ty * 4 + i : 64 + ty * 4 + (i - 4));
        if (r < M) {
            float4 o0 = make_float4(acc[i][0], acc[i][1], acc[i][2], acc[i][3]);
            float4 o1 = make_float4(acc[i][4], acc[i][5], acc[i][6], acc[i][7]);
            *(float4*)&C[(size_t)r * HC + col0 + tx * 4] = o0;
            *(float4*)&C[(size_t)r * HC + col0 + 64 + tx * 4] = o1;
            ushort4 u0 = {f2bf(o0.x), f2bf(o0.y), f2bf(o0.z), f2bf(o0.w)};
            ushort4 u1 = {f2bf(o1.x), f2bf(o1.y), f2bf(o1.z), f2bf(o1.w)};
            *(ushort4*)&C16[(size_t)r * HC + col0 + tx * 4] = u0;
            *(ushort4*)&C16[(size_t)r * HC + col0 + 64 + tx * 4] = u1;
        }
    }
}

// ------------------------------------------------------------------
// per-node attention logits, layout [N, H]
__global__ void alpha_kernel(const float* __restrict__ h, const float* __restrict__ a_src,
                             const float* __restrict__ a_dst, float* __restrict__ asrc,
                             float* __restrict__ adst, int n) {
    int t = blockIdx.x * blockDim.x + threadIdx.x;
    if (t >= n * HEADS) return;
    int node = t >> 3, head = t & 7;
    const float4* hp = (const float4*)(h + (size_t)node * HC + head * HID);
    const float4* w1 = (const float4*)(a_src + head * HID);
    const float4* w2 = (const float4*)(a_dst + head * HID);
    float s1 = 0.f, s2 = 0.f;
#pragma unroll
    for (int q = 0; q < 8; ++q) {
        float4 hv = hp[q], a1 = w1[q], a2 = w2[q];
        s1 += hv.x * a1.x + hv.y * a1.y + hv.z * a1.z + hv.w * a1.w;
        s2 += hv.x * a2.x + hv.y * a2.y + hv.z * a2.z + hv.w * a2.w;
    }
    asrc[t] = s1;
    adst[t] = s2;
}

// ------------------------------------------------------------------
// one wave per node. Pass 1: 8 edge-groups x 8 heads online softmax (asrc is
// L2-resident). Pass 2: 16-edge chunks staged to LDS via async global_load_lds
// (2 rows per instruction, 16 rows in flight, no data VGPRs), weights computed
// in a fully-unrolled masked batch overlapping the staging latency.
template <bool LAST>
__global__ __launch_bounds__(256) void gat_aggregate(
    const unsigned short* __restrict__ hb, const float* __restrict__ asrc,
    const float* __restrict__ adst, const int* __restrict__ row_ptr,
    const int* __restrict__ srcs, const float* __restrict__ bias,
    float* __restrict__ out, const void* __restrict__ batch,
    const int* __restrict__ mode, const float* __restrict__ lin_w,
    float* __restrict__ gsum, float* __restrict__ gcnt, int n) {
    __shared__ unsigned short st[4][16 * 256];   // 4 waves x 16 rows x 512B
    const int wv = (threadIdx.x >> 6) & 3;
    const int lane = threadIdx.x & 63;
    int node = (int)((blockIdx.x * blockDim.x + threadIdx.x) >> 6);
    node = __builtin_amdgcn_readfirstlane(node);
    if (node >= n) return;
    const int l32 = lane & 31;
    const int half = lane >> 5;
    const int h1 = lane & 7;
    const int eg = lane >> 3;      // pass-1 edge group
    const int head = lane >> 3;    // consume head: lane owns channels lane*4..+3
    const int c0 = lane * 4;
    const int beg = row_ptr[node], end = row_ptr[node + 1];
    unsigned short* stw = &st[wv][0];

    // ---- issue chunk-0 staging first; latency hides under pass 1
    if (end > beg) {
        int sv[8];
#pragma unroll
        for (int i = 0; i < 8; ++i) {
            int ja = beg + 2 * i, jb = ja + 1;
            ja = ja < end ? ja : end - 1;
            jb = jb < end ? jb : end - 1;
            int se = srcs[ja], so = srcs[jb];    // wave-uniform -> scalar loads
            sv[i] = half ? so : se;
        }
        __builtin_amdgcn_sched_barrier(0);
#pragma unroll
        for (int i = 0; i < 8; ++i)
            gld_lds16(hb + (size_t)sv[i] * HC + l32 * 8, stw + i * 512);
        __builtin_amdgcn_sched_barrier(0);
    }

    // ---------------- pass 1: per-head max & denom
    float ad1 = adst[node * 8 + h1];
    float m = -1e30f, d = 0.f;
    for (int j = beg + eg; j < end; j += 8) {
        int s = srcs[j];
        float e = asrc[(size_t)s * 8 + h1] + ad1;
        e = e > 0.f ? e : NEG_SLOPE * e;
        float nm = fmaxf(m, e);
        d = d * __expf(m - nm) + __expf(e - nm);
        m = nm;
    }
#pragma unroll
    for (int off = 8; off < 64; off <<= 1) {
        float mo = __shfl_xor(m, off, 64);
        float dd = __shfl_xor(d, off, 64);
        float nm = fmaxf(m, mo);
        d = d * __expf(m - nm) + dd * __expf(mo - nm);
        m = nm;
    }
    float mh = __shfl(m, head, 64);
    float dh = __shfl(d, head, 64);
    // fold in self-loop
    float adh = adst[node * 8 + head];
    float e0 = asrc[node * 8 + head] + adh;
    e0 = e0 > 0.f ? e0 : NEG_SLOPE * e0;
    float nm2 = fmaxf(mh, e0);
    dh = dh * __expf(mh - nm2) + __expf(e0 - nm2);
    mh = nm2;
    float invd = 1.f / (dh + 1e-16f);
    float wself = __expf(e0 - mh) * invd;

    // self row
    ushort4 sr = *(const ushort4*)(hb + (size_t)node * HC + c0);
    float a0 = wself * bf2f(sr.x), a1 = wself * bf2f(sr.y);
    float a2 = wself * bf2f(sr.z), a3 = wself * bf2f(sr.w);

    // ---------------- pass 2: 16-edge chunks
    for (int jc = beg; jc < end; jc += 16) {
        if (jc != beg) {
            int sv[8];
#pragma unroll
            for (int i = 0; i < 8; ++i) {
                int ja = jc + 2 * i, jb = ja + 1;
                ja = ja < end ? ja : end - 1;
                jb = jb < end ? jb : end - 1;
                int se = srcs[ja], so = srcs[jb];
                sv[i] = half ? so : se;
            }
            __builtin_amdgcn_sched_barrier(0);
#pragma unroll
            for (int i = 0; i < 8; ++i)
                gld_lds16(hb + (size_t)sv[i] * HC + l32 * 8, stw + i * 512);
            __builtin_amdgcn_sched_barrier(0);
        }
        const int cnt = (end - jc) < 16 ? (end - jc) : 16;
        // weights: fully unrolled, masked; overlaps the staging latency
        float wgt[16];
#pragma unroll
        for (int jj = 0; jj < 16; ++jj) {
            int j = jc + jj;
            j = j < end ? j : end - 1;
            int s = srcs[j];                            // wave-uniform
            float e = asrc[(size_t)s * 8 + head] + adh; // 32B line, broadcast
            e = e > 0.f ? e : NEG_SLOPE * e;
            float w = __expf(e - mh) * invd;
            wgt[jj] = (jj < cnt) ? w : 0.f;
        }
        asm volatile("s_waitcnt vmcnt(0)" ::: "memory");   // staged rows ready
        __builtin_amdgcn_sched_barrier(0);
#pragma unroll
        for (int jj = 0; jj < 16; ++jj) {
            ushort4 g = *(const ushort4*)(stw + jj * HC + c0);
            a0 = fmaf(wgt[jj], bf2f(g.x), a0);
            a1 = fmaf(wgt[jj], bf2f(g.y), a1);
            a2 = fmaf(wgt[jj], bf2f(g.z), a2);
            a3 = fmaf(wgt[jj], bf2f(g.w), a3);
        }
    }

    float4 b4 = *(const float4*)(bias + c0);
    float o0 = a0 + b4.x, o1 = a1 + b4.y, o2 = a2 + b4.z, o3 = a3 + b4.w;
    o0 = o0 > 0.f ? o0 : __expf(o0) - 1.f;   // ELU
    o1 = o1 > 0.f ? o1 : __expf(o1) - 1.f;
    o2 = o2 > 0.f ? o2 : __expf(o2) - 1.f;
    o3 = o3 > 0.f ? o3 : __expf(o3) - 1.f;
    if (!LAST) {
        *(float4*)(out + (size_t)node * HC + c0) = make_float4(o0, o1, o2, o3);
    } else {
        float4 w4 = *(const float4*)(lin_w + c0);
        float p = o0 * w4.x + o1 * w4.y + o2 * w4.z + o3 * w4.w;
#pragma unroll
        for (int off = 32; off > 0; off >>= 1) p += __shfl_down(p, off, 64);
        if (lane == 0) {
            int g = IDX(batch, node, mode[0]);
            atomicAdd(&gsum[g], p);
            atomicAdd(&gcnt[g], 1.f);
        }
    }
}

__global__ void final_kernel(const float* __restrict__ gsum, const float* __restrict__ gcnt,
                             const float* __restrict__ lin_b, float* __restrict__ outp) {
    int g = blockIdx.x * blockDim.x + threadIdx.x;
    if (g >= GRAPHS) return;
    float c = gcnt[g];
    c = c > 1.f ? c : 1.f;
    outp[g] = gsum[g] / c + lin_b[0];
}

// ------------------------------------------------------------------
extern "C" void kernel_launch(void* const* d_in, const int* in_sizes, int n_in,
                              void* d_out, int out_size, void* d_ws, size_t ws_size,
                              hipStream_t stream) {
    const float* x = (const float*)d_in[0];
    const void* edge = d_in[1];
    const void* batch = d_in[2];
    const float* W[3]    = {(const float*)d_in[3], (const float*)d_in[7],  (const float*)d_in[11]};
    const float* ASRC[3] = {(const float*)d_in[4], (const float*)d_in[8],  (const float*)d_in[12]};
    const float* ADST[3] = {(const float*)d_in[5], (const float*)d_in[9],  (const float*)d_in[13]};
    const float* BIAS[3] = {(const float*)d_in[6], (const float*)d_in[10], (const float*)d_in[14]};
    const float* lin_w = (const float*)d_in[15];
    const float* lin_b = (const float*)d_in[16];
    float* outp = (float*)d_out;

    const int n = in_sizes[0] / 128;  // 50000
    const int e = in_sizes[1] / 2;    // 800000
    const int IN_CH = 128;

    char* ws = (char*)d_ws;
    size_t off = 0;
    auto alloc = [&](size_t bytes) -> void* {
        void* p = ws + off;
        off = (off + bytes + 255) & ~(size_t)255;
        return p;
    };
    float* hbuf   = (float*)alloc((size_t)n * HC * 4);
    float* gbuf   = (float*)alloc((size_t)n * HC * 4);
    unsigned short* hb16 = (unsigned short*)alloc((size_t)n * HC * 2);
    float* as_buf = (float*)alloc((size_t)n * HEADS * 4);
    float* ad_buf = (float*)alloc((size_t)n * HEADS * 4);
    int* hist     = (int*)alloc((size_t)n * 4);          // reused as fill
    int* row_ptr  = (int*)alloc((size_t)(n + 1) * 4);
    int* bsum     = (int*)alloc(1024);
    int* mode     = (int*)alloc(256);
    int* srcs     = (int*)alloc((size_t)e * 4);
    float* gsum   = (float*)alloc((size_t)GRAPHS * 4);
    float* gcnt   = (float*)alloc((size_t)GRAPHS * 4);
    if (off > ws_size) return;

    const int nb = (n + 255) / 256;

    detect_kernel<<<1, 256, 0, stream>>>((const unsigned int*)edge, mode, e);

    // CSR build
    hipMemsetAsync(hist, 0, (size_t)n * 4, stream);
    hist_kernel<<<(e + 255) / 256, 256, 0, stream>>>(edge, mode, hist, e);
    scan1<<<nb, 256, 0, stream>>>(hist, row_ptr, bsum, n);
    scan2<<<1, 256, 0, stream>>>(bsum, nb);
    scan3<<<nb, 256, 0, stream>>>(row_ptr, bsum, n, e);
    hipMemsetAsync(hist, 0, (size_t)n * 4, stream);
    scatter_kernel<<<(e + 255) / 256, 256, 0, stream>>>(edge, mode, row_ptr, hist, srcs, e);

    hipMemsetAsync(gsum, 0, (size_t)GRAPHS * 4, stream);
    hipMemsetAsync(gcnt, 0, (size_t)GRAPHS * 4, stream);

    dim3 gemm_grid((n + 127) / 128, 2);
    const float* cur_in = x;
    int K = IN_CH;
    const int agg_blocks = (n + 3) / 4;   // 1 node/wave, 4 waves/block
    for (int l = 0; l < 3; ++l) {
        gemm128<<<gemm_grid, 256, 0, stream>>>(cur_in, W[l], hbuf, hb16, n, K);
        alpha_kernel<<<(n * HEADS + 255) / 256, 256, 0, stream>>>(hbuf, ASRC[l], ADST[l],
                                                                  as_buf, ad_buf, n);
        if (l < 2) {
            gat_aggregate<false><<<agg_blocks, 256, 0, stream>>>(
                hb16, as_buf, ad_buf, row_ptr, srcs, BIAS[l], gbuf,
                batch, mode, lin_w, gsum, gcnt, n);
        } else {
            gat_aggregate<true><<<agg_blocks, 256, 0, stream>>>(
                hb16, as_buf, ad_buf, row_ptr, srcs, BIAS[l], nullptr,
                batch, mode, lin_w, gsum, gcnt, n);
        }
        cur_in = gbuf;
        K = HC;
    }

    final_kernel<<<2, 256, 0, stream>>>(gsum, gcnt, lin_b, outp);
}

// Round 9
// 679.315 us; speedup vs baseline: 1.3849x; 1.3849x over previous
//
#include <hip/hip_runtime.h>

#define HC 256      // HEADS*HID
#define HEADS 8
#define HID 32
#define GRAPHS 512
#define NEG_SLOPE 0.2f

// ------------------------------------------------------------------
// bf16 helpers (round-to-nearest-even)
__device__ __forceinline__ unsigned short f2bf(float x) {
    unsigned u = __float_as_uint(x);
    return (unsigned short)((u + 0x7fffu + ((u >> 16) & 1u)) >> 16);
}

// int32/int64 index handling (JAX may emit either for edge_index/batch)
__device__ __forceinline__ int IDX(const void* p, long long i, int mode) {
    if (mode) return (int)((const long long*)p)[i];
    return ((const int*)p)[i];
}

__global__ void detect_kernel(const unsigned int* __restrict__ words, int* __restrict__ mode, int e) {
    __shared__ unsigned int red[256];
    unsigned int v = 0;
    int lim = e < 4096 ? e : 4096;
    for (int i = threadIdx.x; i < lim; i += 256) v |= words[2 * i + 1];
    red[threadIdx.x] = v;
    __syncthreads();
    for (int off = 128; off > 0; off >>= 1) {
        if (threadIdx.x < off) red[threadIdx.x] |= red[threadIdx.x + off];
        __syncthreads();
    }
    if (threadIdx.x == 0) *mode = (red[0] == 0u) ? 1 : 0;  // 1 => int64
}

// ------------------------------------------------------------------
// CSR build: histogram -> scan -> scatter
__global__ void hist_kernel(const void* __restrict__ edge, const int* __restrict__ mode,
                            int* __restrict__ hist, int e) {
    int m = mode[0];
    int i = blockIdx.x * blockDim.x + threadIdx.x;
    if (i < e) atomicAdd(&hist[IDX(edge, (long long)e + i, m)], 1);
}

__global__ void scan1(const int* __restrict__ hist, int* __restrict__ excl,
                      int* __restrict__ bsum, int n) {
    __shared__ int buf[256];
    int i = blockIdx.x * 256 + threadIdx.x;
    int v = (i < n) ? hist[i] : 0;
    buf[threadIdx.x] = v;
    __syncthreads();
    for (int off = 1; off < 256; off <<= 1) {
        int t = (threadIdx.x >= (unsigned)off) ? buf[threadIdx.x - off] : 0;
        __syncthreads();
        buf[threadIdx.x] += t;
        __syncthreads();
    }
    if (i < n) excl[i] = buf[threadIdx.x] - v;
    if (threadIdx.x == 255) bsum[blockIdx.x] = buf[255];
}

__global__ void scan2(int* __restrict__ bsum, int nb) {
    __shared__ int buf[256];
    int v = (threadIdx.x < (unsigned)nb) ? bsum[threadIdx.x] : 0;
    buf[threadIdx.x] = v;
    __syncthreads();
    for (int off = 1; off < 256; off <<= 1) {
        int t = (threadIdx.x >= (unsigned)off) ? buf[threadIdx.x - off] : 0;
        __syncthreads();
        buf[threadIdx.x] += t;
        __syncthreads();
    }
    if (threadIdx.x < (unsigned)nb) bsum[threadIdx.x] = buf[threadIdx.x] - v;  // exclusive
}

__global__ void scan3(int* __restrict__ row_ptr, const int* __restrict__ bsum, int n, int e) {
    int i = blockIdx.x * 256 + threadIdx.x;
    if (i < n) row_ptr[i] += bsum[i >> 8];
    if (i == 0) row_ptr[n] = e;
}

__global__ void scatter_kernel(const void* __restrict__ edge, const int* __restrict__ mode,
                               const int* __restrict__ row_ptr, int* __restrict__ fill,
                               int* __restrict__ outs, int e) {
    int m = mode[0];
    int i = blockIdx.x * blockDim.x + threadIdx.x;
    if (i < e) {
        int d = IDX(edge, (long long)e + i, m);
        int pos = row_ptr[d] + atomicAdd(&fill[d], 1);
        outs[pos] = IDX(edge, (long long)i, m);
    }
}

// ------------------------------------------------------------------
// fp32 GEMM: C[M,256] = A[M,K] @ B[K,256], tile 128x128, 8x8 micro (4+4 split)
// Also emits a node-major bf16 copy of C for the gather table.
__device__ __forceinline__ int bswz(int b) { return b ^ ((b >> 3) & 3); }  // involution

__global__ __launch_bounds__(256) void gemm128(const float* __restrict__ A,
                                               const float* __restrict__ B,
                                               float* __restrict__ C,
                                               unsigned short* __restrict__ C16,
                                               int M, int K) {
    __shared__ float As[16][132];
    __shared__ float Bs[16 * 128];
    const int tid = threadIdx.x;
    const int tx = tid & 15, ty = tid >> 4;
    const int row0 = blockIdx.x * 128, col0 = blockIdx.y * 128;
    const int arow = tid >> 2;
    const int acq = tid & 3;
    const int bc = tid & 31;
    const int bk = tid >> 5;
    float acc[8][8] = {};

    for (int k0 = 0; k0 < K; k0 += 16) {
#pragma unroll
        for (int h = 0; h < 2; ++h) {
            int r = arow + 64 * h;
            float4 a = (row0 + r < M)
                ? *(const float4*)&A[(size_t)(row0 + r) * K + k0 + acq * 4]
                : make_float4(0.f, 0.f, 0.f, 0.f);
            As[acq * 4 + 0][r] = a.x;
            As[acq * 4 + 1][r] = a.y;
            As[acq * 4 + 2][r] = a.z;
            As[acq * 4 + 3][r] = a.w;
        }
#pragma unroll
        for (int h = 0; h < 2; ++h) {
            int kk = bk + 8 * h;
            float4 b = *(const float4*)&B[(size_t)(k0 + kk) * HC + col0 + bc * 4];
            *(float4*)&Bs[kk * 128 + 4 * bswz(bc)] = b;
        }
        __syncthreads();
#pragma unroll
        for (int kk = 0; kk < 16; ++kk) {
            float4 a0 = *(const float4*)&As[kk][ty * 4];
            float4 a1 = *(const float4*)&As[kk][64 + ty * 4];
            float4 b0 = *(const float4*)&Bs[kk * 128 + 4 * bswz(tx)];
            float4 b1 = *(const float4*)&Bs[kk * 128 + 4 * bswz(tx + 16)];
            float av[8] = {a0.x, a0.y, a0.z, a0.w, a1.x, a1.y, a1.z, a1.w};
            float bv[8] = {b0.x, b0.y, b0.z, b0.w, b1.x, b1.y, b1.z, b1.w};
#pragma unroll
            for (int i = 0; i < 8; ++i)
#pragma unroll
                for (int j = 0; j < 8; ++j) acc[i][j] = fmaf(av[i], bv[j], acc[i][j]);
        }
        __syncthreads();
    }
#pragma unroll
    for (int i = 0; i < 8; ++i) {
        int r = row0 + (i < 4 ? ty * 4 + i : 64 + ty * 4 + (i - 4));
        if (r < M) {
            float4 o0 = make_float4(acc[i][0], acc[i][1], acc[i][2], acc[i][3]);
            float4 o1 = make_float4(acc[i][4], acc[i][5], acc[i][6], acc[i][7]);
            *(float4*)&C[(size_t)r * HC + col0 + tx * 4] = o0;
            *(float4*)&C[(size_t)r * HC + col0 + 64 + tx * 4] = o1;
            ushort4 u0 = {f2bf(o0.x), f2bf(o0.y), f2bf(o0.z), f2bf(o0.w)};
            ushort4 u1 = {f2bf(o1.x), f2bf(o1.y), f2bf(o1.z), f2bf(o1.w)};
            *(ushort4*)&C16[(size_t)r * HC + col0 + tx * 4] = u0;
            *(ushort4*)&C16[(size_t)r * HC + col0 + 64 + tx * 4] = u1;
        }
    }
}

// ------------------------------------------------------------------
// per-node attention logits, layout [N, H]
__global__ void alpha_kernel(const float* __restrict__ h, const float* __restrict__ a_src,
                             const float* __restrict__ a_dst, float* __restrict__ asrc,
                             float* __restrict__ adst, int n) {
    int t = blockIdx.x * blockDim.x + threadIdx.x;
    if (t >= n * HEADS) return;
    int node = t >> 3, head = t & 7;
    const float4* hp = (const float4*)(h + (size_t)node * HC + head * HID);
    const float4* w1 = (const float4*)(a_src + head * HID);
    const float4* w2 = (const float4*)(a_dst + head * HID);
    float s1 = 0.f, s2 = 0.f;
#pragma unroll
    for (int q = 0; q < 8; ++q) {
        float4 hv = hp[q], a1 = w1[q], a2 = w2[q];
        s1 += hv.x * a1.x + hv.y * a1.y + hv.z * a1.z + hv.w * a1.w;
        s2 += hv.x * a2.x + hv.y * a2.y + hv.z * a2.z + hv.w * a2.w;
    }
    asrc[t] = s1;
    adst[t] = s2;
}

// ------------------------------------------------------------------
// SINGLE-PASS aggregate, no max-shift (logits clamped at 75 -> no overflow;
// softmax without max subtraction is mathematically identical).
// TWO nodes per wave (one per 32-lane half); lane owns 8 channels (uint4 row).
// Per 4-edge group: 4 indep srcs loads -> 4 indep asrc + 4 indep row gathers.
#define ACC_EDGE(gv, wv)                                                      \
    do {                                                                      \
        unsigned _u0 = gv.x, _u1 = gv.y, _u2 = gv.z, _u3 = gv.w;              \
        acc[0] = fmaf(wv, __uint_as_float(_u0 << 16), acc[0]);                \
        acc[1] = fmaf(wv, __uint_as_float(_u0 & 0xffff0000u), acc[1]);        \
        acc[2] = fmaf(wv, __uint_as_float(_u1 << 16), acc[2]);                \
        acc[3] = fmaf(wv, __uint_as_float(_u1 & 0xffff0000u), acc[3]);        \
        acc[4] = fmaf(wv, __uint_as_float(_u2 << 16), acc[4]);                \
        acc[5] = fmaf(wv, __uint_as_float(_u2 & 0xffff0000u), acc[5]);        \
        acc[6] = fmaf(wv, __uint_as_float(_u3 << 16), acc[6]);                \
        acc[7] = fmaf(wv, __uint_as_float(_u3 & 0xffff0000u), acc[7]);        \
    } while (0)

template <bool LAST>
__global__ __launch_bounds__(256) void gat_aggregate(
    const unsigned short* __restrict__ hb, const float* __restrict__ asrc,
    const float* __restrict__ adst, const int* __restrict__ row_ptr,
    const int* __restrict__ srcs, const float* __restrict__ bias,
    float* __restrict__ out, const void* __restrict__ batch,
    const int* __restrict__ mode, const float* __restrict__ lin_w,
    float* __restrict__ gsum, float* __restrict__ gcnt, int n) {
    const int lane = threadIdx.x & 63;
    const int half = lane >> 5;
    const int l32 = lane & 31;
    int wid = (int)((blockIdx.x * blockDim.x + threadIdx.x) >> 6);
    int node = wid * 2 + half;
    if (node >= n) return;
    const int head = l32 >> 2;     // lane's head (channels c0..c0+7 in one head)
    const int c0 = l32 * 8;
    const int beg = row_ptr[node], end = row_ptr[node + 1];

    const float adh = adst[node * 8 + head];
    // self-loop
    float e0 = asrc[node * 8 + head] + adh;
    e0 = e0 > 0.f ? e0 : NEG_SLOPE * e0;
    float w0 = __expf(fminf(e0, 75.f));
    float denom = w0;
    float acc[8] = {};
    {
        uint4 g = *(const uint4*)(hb + (size_t)node * HC + c0);
        ACC_EDGE(g, w0);
    }
    int j = beg;
    for (; j + 4 <= end; j += 4) {
        int s0 = srcs[j], s1 = srcs[j + 1], s2 = srcs[j + 2], s3 = srcs[j + 3];
        uint4 g0 = *(const uint4*)(hb + (size_t)s0 * HC + c0);
        uint4 g1 = *(const uint4*)(hb + (size_t)s1 * HC + c0);
        uint4 g2 = *(const uint4*)(hb + (size_t)s2 * HC + c0);
        uint4 g3 = *(const uint4*)(hb + (size_t)s3 * HC + c0);
        float a0 = asrc[(size_t)s0 * 8 + head], a1 = asrc[(size_t)s1 * 8 + head];
        float a2 = asrc[(size_t)s2 * 8 + head], a3 = asrc[(size_t)s3 * 8 + head];
        float e;
        e = a0 + adh; e = e > 0.f ? e : NEG_SLOPE * e; float x0 = __expf(fminf(e, 75.f));
        e = a1 + adh; e = e > 0.f ? e : NEG_SLOPE * e; float x1 = __expf(fminf(e, 75.f));
        e = a2 + adh; e = e > 0.f ? e : NEG_SLOPE * e; float x2 = __expf(fminf(e, 75.f));
        e = a3 + adh; e = e > 0.f ? e : NEG_SLOPE * e; float x3 = __expf(fminf(e, 75.f));
        denom += x0 + x1 + x2 + x3;
        ACC_EDGE(g0, x0);
        ACC_EDGE(g1, x1);
        ACC_EDGE(g2, x2);
        ACC_EDGE(g3, x3);
    }
    for (; j < end; ++j) {
        int s = srcs[j];
        uint4 g = *(const uint4*)(hb + (size_t)s * HC + c0);
        float e = asrc[(size_t)s * 8 + head] + adh;
        e = e > 0.f ? e : NEG_SLOPE * e;
        float x = __expf(fminf(e, 75.f));
        denom += x;
        ACC_EDGE(g, x);
    }

    const float invd = 1.f / (denom + 1e-16f);
    float4 b0 = *(const float4*)(bias + c0);
    float4 b1 = *(const float4*)(bias + c0 + 4);
    float o[8] = {fmaf(acc[0], invd, b0.x), fmaf(acc[1], invd, b0.y),
                  fmaf(acc[2], invd, b0.z), fmaf(acc[3], invd, b0.w),
                  fmaf(acc[4], invd, b1.x), fmaf(acc[5], invd, b1.y),
                  fmaf(acc[6], invd, b1.z), fmaf(acc[7], invd, b1.w)};
#pragma unroll
    for (int q = 0; q < 8; ++q) o[q] = o[q] > 0.f ? o[q] : __expf(o[q]) - 1.f;  // ELU
    if (!LAST) {
        *(float4*)(out + (size_t)node * HC + c0) = make_float4(o[0], o[1], o[2], o[3]);
        *(float4*)(out + (size_t)node * HC + c0 + 4) = make_float4(o[4], o[5], o[6], o[7]);
    } else {
        float4 wA = *(const float4*)(lin_w + c0);
        float4 wB = *(const float4*)(lin_w + c0 + 4);
        float p = o[0] * wA.x + o[1] * wA.y + o[2] * wA.z + o[3] * wA.w +
                  o[4] * wB.x + o[5] * wB.y + o[6] * wB.z + o[7] * wB.w;
#pragma unroll
        for (int off = 1; off <= 16; off <<= 1) p += __shfl_xor(p, off, 64);  // within half
        if (l32 == 0) {
            int g = IDX(batch, node, mode[0]);
            atomicAdd(&gsum[g], p);
            atomicAdd(&gcnt[g], 1.f);
        }
    }
}

__global__ void final_kernel(const float* __restrict__ gsum, const float* __restrict__ gcnt,
                             const float* __restrict__ lin_b, float* __restrict__ outp) {
    int g = blockIdx.x * blockDim.x + threadIdx.x;
    if (g >= GRAPHS) return;
    float c = gcnt[g];
    c = c > 1.f ? c : 1.f;
    outp[g] = gsum[g] / c + lin_b[0];
}

// ------------------------------------------------------------------
extern "C" void kernel_launch(void* const* d_in, const int* in_sizes, int n_in,
                              void* d_out, int out_size, void* d_ws, size_t ws_size,
                              hipStream_t stream) {
    const float* x = (const float*)d_in[0];
    const void* edge = d_in[1];
    const void* batch = d_in[2];
    const float* W[3]    = {(const float*)d_in[3], (const float*)d_in[7],  (const float*)d_in[11]};
    const float* ASRC[3] = {(const float*)d_in[4], (const float*)d_in[8],  (const float*)d_in[12]};
    const float* ADST[3] = {(const float*)d_in[5], (const float*)d_in[9],  (const float*)d_in[13]};
    const float* BIAS[3] = {(const float*)d_in[6], (const float*)d_in[10], (const float*)d_in[14]};
    const float* lin_w = (const float*)d_in[15];
    const float* lin_b = (const float*)d_in[16];
    float* outp = (float*)d_out;

    const int n = in_sizes[0] / 128;  // 50000
    const int e = in_sizes[1] / 2;    // 800000
    const int IN_CH = 128;

    char* ws = (char*)d_ws;
    size_t off = 0;
    auto alloc = [&](size_t bytes) -> void* {
        void* p = ws + off;
        off = (off + bytes + 255) & ~(size_t)255;
        return p;
    };
    float* hbuf   = (float*)alloc((size_t)n * HC * 4);
    float* gbuf   = (float*)alloc((size_t)n * HC * 4);
    unsigned short* hb16 = (unsigned short*)alloc((size_t)n * HC * 2);
    float* as_buf = (float*)alloc((size_t)n * HEADS * 4);
    float* ad_buf = (float*)alloc((size_t)n * HEADS * 4);
    int* hist     = (int*)alloc((size_t)n * 4);          // reused as fill
    int* row_ptr  = (int*)alloc((size_t)(n + 1) * 4);
    int* bsum     = (int*)alloc(1024);
    int* mode     = (int*)alloc(256);
    int* srcs     = (int*)alloc((size_t)e * 4);
    float* gsum   = (float*)alloc((size_t)GRAPHS * 4);
    float* gcnt   = (float*)alloc((size_t)GRAPHS * 4);
    if (off > ws_size) return;

    const int nb = (n + 255) / 256;

    detect_kernel<<<1, 256, 0, stream>>>((const unsigned int*)edge, mode, e);

    // CSR build
    hipMemsetAsync(hist, 0, (size_t)n * 4, stream);
    hist_kernel<<<(e + 255) / 256, 256, 0, stream>>>(edge, mode, hist, e);
    scan1<<<nb, 256, 0, stream>>>(hist, row_ptr, bsum, n);
    scan2<<<1, 256, 0, stream>>>(bsum, nb);
    scan3<<<nb, 256, 0, stream>>>(row_ptr, bsum, n, e);
    hipMemsetAsync(hist, 0, (size_t)n * 4, stream);
    scatter_kernel<<<(e + 255) / 256, 256, 0, stream>>>(edge, mode, row_ptr, hist, srcs, e);

    hipMemsetAsync(gsum, 0, (size_t)GRAPHS * 4, stream);
    hipMemsetAsync(gcnt, 0, (size_t)GRAPHS * 4, stream);

    dim3 gemm_grid((n + 127) / 128, 2);
    const float* cur_in = x;
    int K = IN_CH;
    const int agg_blocks = (n + 7) / 8;   // 2 nodes/wave, 4 waves/block
    for (int l = 0; l < 3; ++l) {
        gemm128<<<gemm_grid, 256, 0, stream>>>(cur_in, W[l], hbuf, hb16, n, K);
        alpha_kernel<<<(n * HEADS + 255) / 256, 256, 0, stream>>>(hbuf, ASRC[l], ADST[l],
                                                                  as_buf, ad_buf, n);
        if (l < 2) {
            gat_aggregate<false><<<agg_blocks, 256, 0, stream>>>(
                hb16, as_buf, ad_buf, row_ptr, srcs, BIAS[l], gbuf,
                batch, mode, lin_w, gsum, gcnt, n);
        } else {
            gat_aggregate<true><<<agg_blocks, 256, 0, stream>>>(
                hb16, as_buf, ad_buf, row_ptr, srcs, BIAS[l], nullptr,
                batch, mode, lin_w, gsum, gcnt, n);
        }
        cur_in = gbuf;
        K = HC;
    }

    final_kernel<<<2, 256, 0, stream>>>(gsum, gcnt, lin_b, outp);
}